// Round 1
// baseline (200.247 us; speedup 1.0000x reference)
//
#include <hip/hip_runtime.h>
#include <hip/hip_bf16.h>

typedef __attribute__((ext_vector_type(8))) short short8;
typedef __attribute__((ext_vector_type(4))) float f32x4;

#define NPROTO 64
#define DIM    512
#define TAU_INV 5.0f

__device__ __forceinline__ unsigned short f2bf(float f) {
    union { float f; unsigned int u; } v; v.f = f;
    unsigned int r = v.u + 0x7FFFu + ((v.u >> 16) & 1u);  // round-to-nearest-even
    return (unsigned short)(r >> 16);
}

// ---------------------------------------------------------------------------
// Prep: p_norm (normalized protos, bf16, [64][512]) and protos^T (raw, bf16,
// [512][64], d-major so pattern-matmul B-fragments are contiguous 16B).
// ---------------------------------------------------------------------------
__global__ void pb_prep(const float* __restrict__ protos,
                        unsigned short* __restrict__ pnorm,
                        unsigned short* __restrict__ protosT) {
    const int k    = blockIdx.x;   // proto index (64 blocks)
    const int lane = threadIdx.x;  // 64 threads = 1 wave
    const float* row = protos + k * DIM;
    float x[8];
    float ss = 0.0f;
#pragma unroll
    for (int j = 0; j < 8; ++j) {
        x[j] = row[lane * 8 + j];
        ss += x[j] * x[j];
    }
#pragma unroll
    for (int m = 1; m < 64; m <<= 1) ss += __shfl_xor(ss, m, 64);
    const float s = 1.0f / fmaxf(sqrtf(ss), 1e-12f);
    short8 pn;
#pragma unroll
    for (int j = 0; j < 8; ++j) pn[j] = (short)f2bf(x[j] * s);
    *reinterpret_cast<short8*>(pnorm + k * DIM + lane * 8) = pn;
#pragma unroll
    for (int j = 0; j < 8; ++j)
        protosT[(lane * 8 + j) * NPROTO + k] = f2bf(x[j]);
}

// ---------------------------------------------------------------------------
// Main: per wave, 16 rows. logits = (z_raw · p_norm^T) * (5/|z|)  [MFMA],
// softmax in-register on the D-fragment layout, pattern = w · protos [MFMA].
// D-layout (HW-verified): col = lane&15, row = (lane>>4)*4 + reg.
// A/B slots both loaded with slot(g,e) -> k = 8g + e (+32*kt): k-permutation
// invariant, so correct for any internal MFMA k ordering.
// ---------------------------------------------------------------------------
__global__ __launch_bounds__(256) void pb_main(
    const float* __restrict__ seg,
    const unsigned short* __restrict__ pnorm,    // [64][512] bf16
    const unsigned short* __restrict__ protosT,  // [512][64] bf16
    float* __restrict__ out_pat,                 // [N][512]
    float* __restrict__ out_w,                   // [N][64]
    float* __restrict__ out_log) {               // [N][64]

    __shared__ unsigned short wbuf_all[4 * 16 * 64];  // 2KB per wave

    const int wid  = (int)(threadIdx.x >> 6);
    const int lane = (int)(threadIdx.x & 63);
    const int g    = lane >> 4;    // quarter-wave
    const int r16  = lane & 15;
    const long n0  = ((long)blockIdx.x * 4 + wid) * 16;  // first row of tile

    // ---------------- logits matmul: K = 512, 4 proto col-tiles ----------------
    f32x4 acc[4] = {};
    float ss = 0.0f;
    const float* aptr = seg + (n0 + r16) * DIM + g * 8;
#pragma unroll 4
    for (int kt = 0; kt < 16; ++kt) {
        const f32x4 a0 = *reinterpret_cast<const f32x4*>(aptr + kt * 32);
        const f32x4 a1 = *reinterpret_cast<const f32x4*>(aptr + kt * 32 + 4);
        short8 af;
#pragma unroll
        for (int j = 0; j < 4; ++j) {
            ss += a0[j] * a0[j];
            ss += a1[j] * a1[j];
            af[j]     = (short)f2bf(a0[j]);
            af[j + 4] = (short)f2bf(a1[j]);
        }
#pragma unroll
        for (int c = 0; c < 4; ++c) {
            const short8 bf = *reinterpret_cast<const short8*>(
                pnorm + (c * 16 + r16) * DIM + g * 8 + kt * 32);
            acc[c] = __builtin_amdgcn_mfma_f32_16x16x32_bf16(af, bf, acc[c], 0, 0, 0);
        }
    }

    // per-row 1/|z| (lane covered row r16); redistribute to D-layout rows
    ss += __shfl_xor(ss, 16, 64);
    ss += __shfl_xor(ss, 32, 64);
    const float sc_own = TAU_INV / fmaxf(sqrtf(ss), 1e-12f);
    float sc[4];
#pragma unroll
    for (int q = 0; q < 4; ++q) sc[q] = __shfl(sc_own, g * 4 + q, 64);

    float lg[4][4];
#pragma unroll
    for (int c = 0; c < 4; ++c)
#pragma unroll
        for (int q = 0; q < 4; ++q) {
            lg[c][q] = acc[c][q] * sc[q];
            out_log[(n0 + g * 4 + q) * NPROTO + c * 16 + r16] = lg[c][q];
        }

    // ---------------- softmax over 64 protos per row ----------------
    float w[4][4];
#pragma unroll
    for (int q = 0; q < 4; ++q) {
        float mx = fmaxf(fmaxf(lg[0][q], lg[1][q]), fmaxf(lg[2][q], lg[3][q]));
#pragma unroll
        for (int msk = 1; msk < 16; msk <<= 1) mx = fmaxf(mx, __shfl_xor(mx, msk, 64));
        const float e0 = __expf(lg[0][q] - mx);
        const float e1 = __expf(lg[1][q] - mx);
        const float e2 = __expf(lg[2][q] - mx);
        const float e3 = __expf(lg[3][q] - mx);
        float sum = e0 + e1 + e2 + e3;
#pragma unroll
        for (int msk = 1; msk < 16; msk <<= 1) sum += __shfl_xor(sum, msk, 64);
        const float inv = 1.0f / sum;
        w[0][q] = e0 * inv; w[1][q] = e1 * inv; w[2][q] = e2 * inv; w[3][q] = e3 * inv;
    }

    // store w + LDS transpose (D-layout -> A-layout), XOR-swizzled vs 16-way conflict
    unsigned short* wb = wbuf_all + wid * (16 * 64);
#pragma unroll
    for (int c = 0; c < 4; ++c)
#pragma unroll
        for (int q = 0; q < 4; ++q) {
            out_w[(n0 + g * 4 + q) * NPROTO + c * 16 + r16] = w[c][q];
            const int row  = g * 4 + q;
            const int col  = c * 16 + r16;
            const int byte = (row * 128 + col * 2) ^ ((row & 7) << 4);
            *reinterpret_cast<unsigned short*>(reinterpret_cast<char*>(wb) + byte) =
                f2bf(w[c][q]);
        }

    __syncthreads();  // cheap; guarantees LDS writes visible (incl. lgkmcnt drain)

    short8 wa0, wa1;
    {
        const int row = r16;
        const int b0 = (row * 128 + g * 16)      ^ ((row & 7) << 4);
        const int b1 = (row * 128 + g * 16 + 64) ^ ((row & 7) << 4);
        wa0 = *reinterpret_cast<const short8*>(reinterpret_cast<char*>(wb) + b0);
        wa1 = *reinterpret_cast<const short8*>(reinterpret_cast<char*>(wb) + b1);
    }

    // ---------------- pattern = w · protos : K = 64, 32 col-tiles ----------------
#pragma unroll 2
    for (int cp = 0; cp < 32; ++cp) {
        const unsigned short* bp = protosT + (cp * 16 + r16) * NPROTO + g * 8;
        const short8 b0 = *reinterpret_cast<const short8*>(bp);
        const short8 b1 = *reinterpret_cast<const short8*>(bp + 32);
        f32x4 pacc = {};
        pacc = __builtin_amdgcn_mfma_f32_16x16x32_bf16(wa0, b0, pacc, 0, 0, 0);
        pacc = __builtin_amdgcn_mfma_f32_16x16x32_bf16(wa1, b1, pacc, 0, 0, 0);
#pragma unroll
        for (int q = 0; q < 4; ++q)
            out_pat[(n0 + g * 4 + q) * DIM + cp * 16 + r16] = pacc[q];
    }
}

extern "C" void kernel_launch(void* const* d_in, const int* in_sizes, int n_in,
                              void* d_out, int out_size, void* d_ws, size_t ws_size,
                              hipStream_t stream) {
    const float* seg    = (const float*)d_in[0];
    const float* protos = (const float*)d_in[1];
    const int N = in_sizes[0] / DIM;  // 131072

    float* out     = (float*)d_out;
    float* out_pat = out;
    float* out_w   = out_pat + (size_t)N * DIM;
    float* out_log = out_w + (size_t)N * NPROTO;

    unsigned short* pnorm   = (unsigned short*)d_ws;          // 64KB
    unsigned short* protosT = pnorm + NPROTO * DIM;           // 64KB

    pb_prep<<<NPROTO, 64, 0, stream>>>(protos, pnorm, protosT);
    pb_main<<<N / 64, 256, 0, stream>>>(seg, pnorm, protosT, out_pat, out_w, out_log);
}

// Round 2
// 167.606 us; speedup vs baseline: 1.1948x; 1.1948x over previous
//
#include <hip/hip_runtime.h>
#include <hip/hip_bf16.h>

typedef __attribute__((ext_vector_type(8))) short short8;
typedef __attribute__((ext_vector_type(4))) float f32x4;

#define NPROTO 64
#define DIM    512
#define TAU_INV 5.0f

__device__ __forceinline__ unsigned short f2bf(float f) {
    union { float f; unsigned int u; } v; v.f = f;
    unsigned int r = v.u + 0x7FFFu + ((v.u >> 16) & 1u);  // round-to-nearest-even
    return (unsigned short)(r >> 16);
}

// ---------------------------------------------------------------------------
// Prep: p_norm (normalized protos, bf16, [64][512]) and protos^T (raw, bf16,
// [512][64]).
// ---------------------------------------------------------------------------
__global__ void pb_prep(const float* __restrict__ protos,
                        unsigned short* __restrict__ pnorm,
                        unsigned short* __restrict__ protosT) {
    const int k    = blockIdx.x;
    const int lane = threadIdx.x;
    const float* row = protos + k * DIM;
    float x[8];
    float ss = 0.0f;
#pragma unroll
    for (int j = 0; j < 8; ++j) {
        x[j] = row[lane * 8 + j];
        ss += x[j] * x[j];
    }
#pragma unroll
    for (int m = 1; m < 64; m <<= 1) ss += __shfl_xor(ss, m, 64);
    const float s = 1.0f / fmaxf(sqrtf(ss), 1e-12f);
    short8 pn;
#pragma unroll
    for (int j = 0; j < 8; ++j) pn[j] = (short)f2bf(x[j] * s);
    *reinterpret_cast<short8*>(pnorm + k * DIM + lane * 8) = pn;
#pragma unroll
    for (int j = 0; j < 8; ++j)
        protosT[(lane * 8 + j) * NPROTO + k] = f2bf(x[j]);
}

// ---------------------------------------------------------------------------
// Main v2: 32 rows per wave (2 MFMA A-fragments sharing every B-fragment),
// explicit next-kt A prefetch. D-layout: col = lane&15, row = (lane>>4)*4+reg.
// ---------------------------------------------------------------------------
__global__ __launch_bounds__(256, 4) void pb_main(
    const float* __restrict__ seg,
    const unsigned short* __restrict__ pnorm,    // [64][512] bf16
    const unsigned short* __restrict__ protosT,  // [512][64] bf16
    float* __restrict__ out_pat,                 // [N][512]
    float* __restrict__ out_w,                   // [N][64]
    float* __restrict__ out_log) {               // [N][64]

    __shared__ unsigned short wbuf_all[4 * 2 * 16 * 64];  // 16KB: 2KB/frag

    const int wid  = (int)(threadIdx.x >> 6);
    const int lane = (int)(threadIdx.x & 63);
    const int g    = lane >> 4;
    const int r16  = lane & 15;
    const long n0  = ((long)blockIdx.x * 4 + wid) * 32;  // first of 32 rows

    // ---------------- logits matmul: K=512, 2 row-frags x 4 col-tiles --------
    f32x4 acc0[4] = {}, acc1[4] = {};
    float ss0 = 0.0f, ss1 = 0.0f;
    const float* ap0 = seg + (n0 + r16) * DIM + g * 8;
    const float* ap1 = ap0 + 16 * DIM;

    f32x4 a00 = *reinterpret_cast<const f32x4*>(ap0);
    f32x4 a01 = *reinterpret_cast<const f32x4*>(ap0 + 4);
    f32x4 a10 = *reinterpret_cast<const f32x4*>(ap1);
    f32x4 a11 = *reinterpret_cast<const f32x4*>(ap1 + 4);

#pragma unroll
    for (int kt = 0; kt < 16; ++kt) {
        f32x4 n00, n01, n10, n11;
        if (kt < 15) {  // issue next-kt loads before touching current data
            n00 = *reinterpret_cast<const f32x4*>(ap0 + (kt + 1) * 32);
            n01 = *reinterpret_cast<const f32x4*>(ap0 + (kt + 1) * 32 + 4);
            n10 = *reinterpret_cast<const f32x4*>(ap1 + (kt + 1) * 32);
            n11 = *reinterpret_cast<const f32x4*>(ap1 + (kt + 1) * 32 + 4);
        }
        short8 af0, af1;
#pragma unroll
        for (int j = 0; j < 4; ++j) {
            ss0 += a00[j] * a00[j] + a01[j] * a01[j];
            ss1 += a10[j] * a10[j] + a11[j] * a11[j];
            af0[j] = (short)f2bf(a00[j]); af0[j + 4] = (short)f2bf(a01[j]);
            af1[j] = (short)f2bf(a10[j]); af1[j + 4] = (short)f2bf(a11[j]);
        }
        const unsigned short* bbase = pnorm + r16 * DIM + g * 8 + kt * 32;
#pragma unroll
        for (int c = 0; c < 4; ++c) {
            const short8 bf = *reinterpret_cast<const short8*>(bbase + c * 16 * DIM);
            acc0[c] = __builtin_amdgcn_mfma_f32_16x16x32_bf16(af0, bf, acc0[c], 0, 0, 0);
            acc1[c] = __builtin_amdgcn_mfma_f32_16x16x32_bf16(af1, bf, acc1[c], 0, 0, 0);
        }
        if (kt < 15) { a00 = n00; a01 = n01; a10 = n10; a11 = n11; }
    }

    // per-row 1/|z|, redistribute to D-layout rows (per fragment)
    ss0 += __shfl_xor(ss0, 16, 64); ss0 += __shfl_xor(ss0, 32, 64);
    ss1 += __shfl_xor(ss1, 16, 64); ss1 += __shfl_xor(ss1, 32, 64);
    const float sco0 = TAU_INV / fmaxf(sqrtf(ss0), 1e-12f);
    const float sco1 = TAU_INV / fmaxf(sqrtf(ss1), 1e-12f);
    float sc0[4], sc1[4];
#pragma unroll
    for (int q = 0; q < 4; ++q) {
        sc0[q] = __shfl(sco0, g * 4 + q, 64);
        sc1[q] = __shfl(sco1, g * 4 + q, 64);
    }

    float lg0[4][4], lg1[4][4];
#pragma unroll
    for (int c = 0; c < 4; ++c)
#pragma unroll
        for (int q = 0; q < 4; ++q) {
            lg0[c][q] = acc0[c][q] * sc0[q];
            lg1[c][q] = acc1[c][q] * sc1[q];
            out_log[(n0 + g * 4 + q) * NPROTO + c * 16 + r16]      = lg0[c][q];
            out_log[(n0 + 16 + g * 4 + q) * NPROTO + c * 16 + r16] = lg1[c][q];
        }

    // ---------------- softmax over 64 protos per row -------------------------
    float w0[4][4], w1[4][4];
#pragma unroll
    for (int q = 0; q < 4; ++q) {
        float mx0 = fmaxf(fmaxf(lg0[0][q], lg0[1][q]), fmaxf(lg0[2][q], lg0[3][q]));
        float mx1 = fmaxf(fmaxf(lg1[0][q], lg1[1][q]), fmaxf(lg1[2][q], lg1[3][q]));
#pragma unroll
        for (int msk = 1; msk < 16; msk <<= 1) {
            mx0 = fmaxf(mx0, __shfl_xor(mx0, msk, 64));
            mx1 = fmaxf(mx1, __shfl_xor(mx1, msk, 64));
        }
        float e0[4], e1[4], sum0 = 0.0f, sum1 = 0.0f;
#pragma unroll
        for (int c = 0; c < 4; ++c) {
            e0[c] = __expf(lg0[c][q] - mx0); sum0 += e0[c];
            e1[c] = __expf(lg1[c][q] - mx1); sum1 += e1[c];
        }
#pragma unroll
        for (int msk = 1; msk < 16; msk <<= 1) {
            sum0 += __shfl_xor(sum0, msk, 64);
            sum1 += __shfl_xor(sum1, msk, 64);
        }
        const float i0 = 1.0f / sum0, i1 = 1.0f / sum1;
#pragma unroll
        for (int c = 0; c < 4; ++c) { w0[c][q] = e0[c] * i0; w1[c][q] = e1[c] * i1; }
    }

    // store w + LDS transpose (D-layout -> A-layout), XOR swizzle vs bank conflicts
    unsigned short* wb0 = wbuf_all + (wid * 2 + 0) * (16 * 64);
    unsigned short* wb1 = wbuf_all + (wid * 2 + 1) * (16 * 64);
#pragma unroll
    for (int c = 0; c < 4; ++c)
#pragma unroll
        for (int q = 0; q < 4; ++q) {
            out_w[(n0 + g * 4 + q) * NPROTO + c * 16 + r16]      = w0[c][q];
            out_w[(n0 + 16 + g * 4 + q) * NPROTO + c * 16 + r16] = w1[c][q];
            const int row  = g * 4 + q;
            const int col  = c * 16 + r16;
            const int byte = (row * 128 + col * 2) ^ ((row & 7) << 4);
            *reinterpret_cast<unsigned short*>(reinterpret_cast<char*>(wb0) + byte) = f2bf(w0[c][q]);
            *reinterpret_cast<unsigned short*>(reinterpret_cast<char*>(wb1) + byte) = f2bf(w1[c][q]);
        }

    __syncthreads();

    short8 wa[2][2];
    {
        const int row = r16;
        const int b0 = (row * 128 + g * 16)      ^ ((row & 7) << 4);
        const int b1 = (row * 128 + g * 16 + 64) ^ ((row & 7) << 4);
        wa[0][0] = *reinterpret_cast<const short8*>(reinterpret_cast<char*>(wb0) + b0);
        wa[0][1] = *reinterpret_cast<const short8*>(reinterpret_cast<char*>(wb0) + b1);
        wa[1][0] = *reinterpret_cast<const short8*>(reinterpret_cast<char*>(wb1) + b0);
        wa[1][1] = *reinterpret_cast<const short8*>(reinterpret_cast<char*>(wb1) + b1);
    }

    // ---------------- pattern = w · protos : K=64, 32 col-tiles --------------
#pragma unroll 2
    for (int cp = 0; cp < 32; ++cp) {
        const unsigned short* bp = protosT + (cp * 16 + r16) * NPROTO + g * 8;
        const short8 b0 = *reinterpret_cast<const short8*>(bp);
        const short8 b1 = *reinterpret_cast<const short8*>(bp + 32);
        f32x4 p0 = {}, p1 = {};
        p0 = __builtin_amdgcn_mfma_f32_16x16x32_bf16(wa[0][0], b0, p0, 0, 0, 0);
        p0 = __builtin_amdgcn_mfma_f32_16x16x32_bf16(wa[0][1], b1, p0, 0, 0, 0);
        p1 = __builtin_amdgcn_mfma_f32_16x16x32_bf16(wa[1][0], b0, p1, 0, 0, 0);
        p1 = __builtin_amdgcn_mfma_f32_16x16x32_bf16(wa[1][1], b1, p1, 0, 0, 0);
#pragma unroll
        for (int q = 0; q < 4; ++q) {
            out_pat[(n0 + g * 4 + q) * DIM + cp * 16 + r16]      = p0[q];
            out_pat[(n0 + 16 + g * 4 + q) * DIM + cp * 16 + r16] = p1[q];
        }
    }
}

extern "C" void kernel_launch(void* const* d_in, const int* in_sizes, int n_in,
                              void* d_out, int out_size, void* d_ws, size_t ws_size,
                              hipStream_t stream) {
    const float* seg    = (const float*)d_in[0];
    const float* protos = (const float*)d_in[1];
    const int N = in_sizes[0] / DIM;  // 131072

    float* out     = (float*)d_out;
    float* out_pat = out;
    float* out_w   = out_pat + (size_t)N * DIM;
    float* out_log = out_w + (size_t)N * NPROTO;

    unsigned short* pnorm   = (unsigned short*)d_ws;
    unsigned short* protosT = pnorm + NPROTO * DIM;

    pb_prep<<<NPROTO, 64, 0, stream>>>(protos, pnorm, protosT);
    pb_main<<<N / 128, 256, 0, stream>>>(seg, pnorm, protosT, out_pat, out_w, out_log);
}